// Round 13
// baseline (127.420 us; speedup 1.0000x reference)
//
#include <hip/hip_runtime.h>
#include <hip/hip_fp16.h>

#define NN 100000
#define NE 1000000
#define FIN 64
#define FHID 32
#define FH 16                     // half of FHID (column-split)
#define NB 782                    // dst>>7 buckets
#define BNODES 128
#define NCH 256                   // edge chunks
#define CH ((NE + NCH - 1) / NCH) // 3907
#define GEMB ((NN + 31) / 32)     // 3125

typedef float f4v __attribute__((ext_vector_type(4)));
typedef float f2v __attribute__((ext_vector_type(2)));

union H8 { __half2 h2[4]; float4 f4; };
union H4 { __half2 h2[2]; float2 f2; };

// ---------------- pass A: per-chunk LDS bucket histogram; phist[k][b] chunk-major ----------------
__global__ __launch_bounds__(256) void k_bhist(const int* __restrict__ dst, int* __restrict__ phist) {
    __shared__ int lh[NB];
    for (int i = threadIdx.x; i < NB; i += 256) lh[i] = 0;
    __syncthreads();
    int k = blockIdx.x;
    int e0 = k * CH, e1 = min(e0 + CH, NE);
    for (int e = e0 + threadIdx.x; e < e1; e += 256) atomicAdd(&lh[dst[e] >> 7], 1);
    __syncthreads();
    for (int b = threadIdx.x; b < NB; b += 256) phist[(size_t)k * NB + b] = lh[b];
}

// ---------------- pass B1: per-bucket scan over 256 chunks ----------------
__global__ __launch_bounds__(256) void k_bscan(int* __restrict__ phist, int* __restrict__ btot) {
    int b = blockIdx.x;
    int k = threadIdx.x;
    int v = phist[(size_t)k * NB + b];
    int lane = k & 63, wv = k >> 6;
    int incl = v;
#pragma unroll
    for (int s = 1; s < 64; s <<= 1) {
        int t = __shfl_up(incl, s, 64);
        if (lane >= s) incl += t;
    }
    __shared__ int wt[4];
    if (lane == 63) wt[wv] = incl;
    __syncthreads();
    int add = 0;
#pragma unroll
    for (int w = 0; w < 4; ++w) add += (w < wv) ? wt[w] : 0;
    phist[(size_t)k * NB + b] = add + incl - v;
    if (k == 255) btot[b] = add + incl;
}

// ---------------- pass B2: cross-bucket scan (1 block) ----------------
__global__ __launch_bounds__(1024) void k_bbase(const int* __restrict__ btot, int* __restrict__ bbase,
                                                int* __restrict__ off) {
    __shared__ int s[1024];
    int b = threadIdx.x;
    int v = (b < NB) ? btot[b] : 0;
    s[b] = v;
    __syncthreads();
    for (int d = 1; d < 1024; d <<= 1) {
        int t = (b >= d) ? s[b - d] : 0;
        __syncthreads();
        s[b] += t;
        __syncthreads();
    }
    if (b < NB) bbase[b] = s[b] - v;
    if (b == 0) { bbase[NB] = NE; off[NN] = NE; }
}

// ---------------- pass C: bucket-scatter (packed 4B) || gemm1 -> h1A/h1B halves ----------------
__global__ __launch_bounds__(256) void k_scatter_gemm1(const int* __restrict__ ei,
                                                       const int* __restrict__ phist,
                                                       const int* __restrict__ bbase,
                                                       int* __restrict__ ebuf,
                                                       const float* __restrict__ x,
                                                       const float* __restrict__ W1,
                                                       __half* __restrict__ h1A,
                                                       __half* __restrict__ h1B) {
    int r = blockIdx.x;
    bool issc;
    int id;
    if (r < 2 * NCH) { issc = !(r & 1); id = r >> 1; }
    else             { issc = false;    id = r - NCH; }
    if (issc) {
        __shared__ int lh[NB];
        __shared__ int lbase[NB];
        int k = id;
        for (int b = threadIdx.x; b < NB; b += 256) {
            lh[b] = 0;
            lbase[b] = bbase[b] + phist[(size_t)k * NB + b];
        }
        __syncthreads();
        int e0 = k * CH, e1 = min(e0 + CH, NE);
        for (int e = e0 + threadIdx.x; e < e1; e += 256) {
            int s = ei[e], d = ei[NE + e];
            int bb = d >> 7;
            int rr = atomicAdd(&lh[bb], 1);
            ebuf[lbase[bb] + rr] = s * BNODES + (d & 127);
        }
        return;
    }
    // gemm1: h1 = x @ W1 (fp16, column-split halves; k_csr scales by dis in place)
    __shared__ float Wl[FIN * FHID];
    for (int t = threadIdx.x; t < FIN * FHID / 4; t += 256)
        reinterpret_cast<float4*>(Wl)[t] = reinterpret_cast<const float4*>(W1)[t];
    __syncthreads();
    int row = id * 32 + (threadIdx.x >> 3);
    int l = threadIdx.x & 7;
    if (row >= NN) return;
    const float4* xr = reinterpret_cast<const float4*>(x + (size_t)row * FIN);
    float4 acc = make_float4(0.f, 0.f, 0.f, 0.f);
#pragma unroll
    for (int k4 = 0; k4 < FIN / 4; ++k4) {
        float4 a4 = xr[k4];
#pragma unroll
        for (int j = 0; j < 4; ++j) {
            float a = j == 0 ? a4.x : j == 1 ? a4.y : j == 2 ? a4.z : a4.w;
            const float4 wv = *reinterpret_cast<const float4*>(Wl + (k4 * 4 + j) * FHID + l * 4);
            acc.x += a * wv.x; acc.y += a * wv.y; acc.z += a * wv.z; acc.w += a * wv.w;
        }
    }
    H4 u;
    u.h2[0] = __floats2half2_rn(acc.x, acc.y);
    u.h2[1] = __floats2half2_rn(acc.z, acc.w);
    __half* hb = (l < 4) ? h1A : h1B;
    *reinterpret_cast<float2*>(hb + (size_t)row * FH + (l & 3) * 4) = u.f2;
}

// ---------------- pass D: per-bucket node CSR + off + dis + in-place scale h1A/h1B *= dis ----------------
__global__ __launch_bounds__(256) void k_csr(const int* __restrict__ ebuf, const int* __restrict__ bbase,
                                             int* __restrict__ off, float* __restrict__ dis,
                                             int* __restrict__ csr, __half* __restrict__ h1A,
                                             __half* __restrict__ h1B) {
    __shared__ int nh[BNODES];
    __shared__ int ofl[BNODES];
    __shared__ float sdis[BNODES];
    int b = blockIdx.x;
    int n0 = b * BNODES;
    int ebeg = bbase[b], eend = bbase[b + 1];
    int ld = threadIdx.x;
    if (ld < BNODES) nh[ld] = 0;
    __syncthreads();
    for (int e = ebeg + threadIdx.x; e < eend; e += 256) atomicAdd(&nh[ebuf[e] & 127], 1);
    __syncthreads();
    int dval = (ld < BNODES) ? nh[ld] : 0;
    if (ld < BNODES) ofl[ld] = dval;
    __syncthreads();
    for (int s = 1; s < BNODES; s <<= 1) {
        int t = 0;
        if (ld < BNODES && ld >= s) t = ofl[ld - s];
        __syncthreads();
        if (ld < BNODES) ofl[ld] += t;
        __syncthreads();
    }
    if (ld < BNODES) {
        ofl[ld] -= dval;
        float dv = rsqrtf((float)dval + 1.0f);
        sdis[ld] = dv;
        int n = n0 + ld;
        if (n < NN) {
            off[n] = ebeg + ofl[ld];
            dis[n] = dv;
        }
        nh[ld] = 0;
    }
    __syncthreads();
    for (int e = ebeg + threadIdx.x; e < eend; e += 256) {
        int v = ebuf[e];
        int ldd = v & 127;
        int r = atomicAdd(&nh[ldd], 1);
        csr[ebeg + ofl[ldd] + r] = v >> 7;
    }
    // scale both h1 halves in place: thread = (node-in-bucket, half)
    int i = ld >> 1, half = ld & 1;
    int n = n0 + i;
    if (n < NN) {
        float dv = sdis[i];
        __half* hb = half ? h1B : h1A;
        float4* pr = reinterpret_cast<float4*>(hb + (size_t)n * FH);
#pragma unroll
        for (int j = 0; j < 2; ++j) {
            float4 v4 = pr[j];
            __half2* hp = reinterpret_cast<__half2*>(&v4);
#pragma unroll
            for (int u = 0; u < 4; ++u) {
                float2 f = __half22float2(hp[u]);
                hp[u] = __floats2half2_rn(f.x * dv, f.y * dv);
            }
            pr[j] = v4;
        }
    }
}

// ---------------- half-width gather: 16 lanes/node (4 nbr x 4 col), pure-sum, L2-resident half ----------------
// hin: prescaled half features (NN x 16 fp16 = 3.2 MB, fits one XCD L2).
// RELU=1 (layer1): out = dn * relu(dn*acc + bias);  RELU=0 (layer2 pre-GEMM): out = dn*acc.
template <int RELU>
__global__ __launch_bounds__(256) void k_gather(const int* __restrict__ off, const int* __restrict__ csr,
                                                const float* __restrict__ dis,
                                                const __half* __restrict__ hin,
                                                const float* __restrict__ bias,
                                                __half* __restrict__ out) {
    int t = blockIdx.x * 256 + threadIdx.x;
    int n = t >> 4;
    int l = t & 15;
    int q = l >> 2, c = l & 3;
    float dn = dis[n];
    int beg = off[n], end = off[n + 1];
    float acc[4] = {0.f, 0.f, 0.f, 0.f};
    int p = beg + q;
    int s = (p < end) ? __builtin_nontemporal_load(csr + p) : 0;
    for (; p < end; p += 4) {
        int scur = s;
        if (p + 4 < end) s = __builtin_nontemporal_load(csr + p + 4);  // NT: don't evict h lines
        float2 v = *reinterpret_cast<const float2*>(hin + (size_t)scur * FH + c * 4);
        const __half2* hp = reinterpret_cast<const __half2*>(&v);
        float2 f0 = __half22float2(hp[0]);
        float2 f1 = __half22float2(hp[1]);
        acc[0] += f0.x; acc[1] += f0.y; acc[2] += f1.x; acc[3] += f1.y;
    }
#pragma unroll
    for (int j = 0; j < 4; ++j) {
        acc[j] += __shfl_xor(acc[j], 4);
        acc[j] += __shfl_xor(acc[j], 8);
    }
    if (q == 0) {
        float2 sv = *reinterpret_cast<const float2*>(hin + (size_t)n * FH + c * 4);
        const __half2* sp = reinterpret_cast<const __half2*>(&sv);
        float2 s0 = __half22float2(sp[0]);
        float2 s1 = __half22float2(sp[1]);
        acc[0] += s0.x; acc[1] += s0.y; acc[2] += s1.x; acc[3] += s1.y;
        float r[4];
        if (RELU) {
            const float4 bb = *reinterpret_cast<const float4*>(bias + c * 4);
            float pre[4] = {dn * acc[0] + bb.x, dn * acc[1] + bb.y,
                            dn * acc[2] + bb.z, dn * acc[3] + bb.w};
#pragma unroll
            for (int j = 0; j < 4; ++j) {
                float v2 = pre[j] > 0.f ? pre[j] : 0.f;
                r[j] = dn * v2;  // prescale for next layer
            }
        } else {
#pragma unroll
            for (int j = 0; j < 4; ++j) r[j] = dn * acc[j];
        }
        H4 o;
        o.h2[0] = __floats2half2_rn(r[0], r[1]);
        o.h2[1] = __floats2half2_rn(r[2], r[3]);
        __builtin_nontemporal_store(*reinterpret_cast<const f2v*>(&o.f2),
                                    reinterpret_cast<f2v*>(out + (size_t)n * FH + c * 4));
    }
}

// ---------------- final GEMM: out = [aggA|aggB] @ W2 + b2   [NN,32]x[32,64] ----------------
__global__ __launch_bounds__(256) void k_mm2(const __half* __restrict__ aggA, const __half* __restrict__ aggB,
                                             const float* __restrict__ W2, const float* __restrict__ b2,
                                             float* __restrict__ out) {
    __shared__ float WL[FHID * FIN];  // 8 KB
    for (int t = threadIdx.x; t < FHID * FIN / 4; t += 256)
        reinterpret_cast<float4*>(WL)[t] = reinterpret_cast<const float4*>(W2)[t];
    __syncthreads();
    int row = blockIdx.x * 32 + (threadIdx.x >> 3);
    int l = threadIdx.x & 7;
    int c0 = l * 8;
    float a[32];
    {
        const float4* pa = reinterpret_cast<const float4*>(aggA + (size_t)row * FH);
        const float4* pb = reinterpret_cast<const float4*>(aggB + (size_t)row * FH);
#pragma unroll
        for (int h = 0; h < 2; ++h) {
            float4 v4 = pa[h];
            const __half2* hp = reinterpret_cast<const __half2*>(&v4);
#pragma unroll
            for (int j = 0; j < 4; ++j) {
                float2 f = __half22float2(hp[j]);
                a[h * 8 + 2 * j] = f.x;
                a[h * 8 + 2 * j + 1] = f.y;
            }
        }
#pragma unroll
        for (int h = 0; h < 2; ++h) {
            float4 v4 = pb[h];
            const __half2* hp = reinterpret_cast<const __half2*>(&v4);
#pragma unroll
            for (int j = 0; j < 4; ++j) {
                float2 f = __half22float2(hp[j]);
                a[16 + h * 8 + 2 * j] = f.x;
                a[16 + h * 8 + 2 * j + 1] = f.y;
            }
        }
    }
    float4 acc0 = *reinterpret_cast<const float4*>(b2 + c0);
    float4 acc1 = *reinterpret_cast<const float4*>(b2 + c0 + 4);
#pragma unroll
    for (int k = 0; k < FHID; ++k) {
        float av = a[k];
        const float* wr = WL + k * FIN + c0;
        const float4 w0 = *reinterpret_cast<const float4*>(wr);
        const float4 w1 = *reinterpret_cast<const float4*>(wr + 4);
        acc0.x += av * w0.x; acc0.y += av * w0.y; acc0.z += av * w0.z; acc0.w += av * w0.w;
        acc1.x += av * w1.x; acc1.y += av * w1.y; acc1.z += av * w1.z; acc1.w += av * w1.w;
    }
    float* o = out + (size_t)row * FIN + c0;
    __builtin_nontemporal_store(*reinterpret_cast<const f4v*>(&acc0), reinterpret_cast<f4v*>(o));
    __builtin_nontemporal_store(*reinterpret_cast<const f4v*>(&acc1), reinterpret_cast<f4v*>(o + 4));
}

extern "C" void kernel_launch(void* const* d_in, const int* in_sizes, int n_in,
                              void* d_out, int out_size, void* d_ws, size_t ws_size,
                              hipStream_t stream) {
    const float* x  = (const float*)d_in[0];
    const int*   ei = (const int*)d_in[1];
    const float* W1 = (const float*)d_in[2];
    const float* b1 = (const float*)d_in[3];
    const float* W2 = (const float*)d_in[4];
    const float* b2 = (const float*)d_in[5];
    float* out = (float*)d_out;

    char* w = (char*)d_ws;
    auto align = [](size_t v) { return (v + 255) & ~(size_t)255; };
    int*    phist = (int*)w;    w += align((size_t)NCH * NB * 4);
    int*    btot  = (int*)w;    w += align((size_t)NB * 4);
    int*    bbase = (int*)w;    w += align((size_t)(NB + 1) * 4);
    int*    ebuf  = (int*)w;    w += align((size_t)NE * 4);
    int*    off   = (int*)w;    w += align((size_t)(NN + 1) * 4);
    float*  dis   = (float*)w;  w += align((size_t)NN * 4);
    int*    csr   = (int*)w;    w += align((size_t)NE * 4);
    __half* h1A   = (__half*)w; w += align((size_t)NN * FH * 2);
    __half* h1B   = (__half*)w; w += align((size_t)NN * FH * 2);
    __half* hbA   = (__half*)w; w += align((size_t)NN * FH * 2);
    __half* hbB   = (__half*)w; w += align((size_t)NN * FH * 2);
    __half* agA   = (__half*)w; w += align((size_t)NN * FH * 2);
    __half* agB   = (__half*)w; w += align((size_t)NN * FH * 2);

    const int* dst = ei + NE;
    k_bhist<<<NCH, 256, 0, stream>>>(dst, phist);
    k_bscan<<<NB, 256, 0, stream>>>(phist, btot);
    k_bbase<<<1, 1024, 0, stream>>>(btot, bbase, off);
    k_scatter_gemm1<<<NCH + GEMB, 256, 0, stream>>>(ei, phist, bbase, ebuf, x, W1, h1A, h1B);
    k_csr<<<NB, 256, 0, stream>>>(ebuf, bbase, off, dis, csr, h1A, h1B);
    // layer-1 gathers, one L2-resident half at a time
    k_gather<1><<<(NN * 16) / 256, 256, 0, stream>>>(off, csr, dis, h1A, b1, hbA);
    k_gather<1><<<(NN * 16) / 256, 256, 0, stream>>>(off, csr, dis, h1B, b1 + FH, hbB);
    // layer-2 gathers
    k_gather<0><<<(NN * 16) / 256, 256, 0, stream>>>(off, csr, dis, hbA, nullptr, agA);
    k_gather<0><<<(NN * 16) / 256, 256, 0, stream>>>(off, csr, dis, hbB, nullptr, agB);
    // final dense GEMM + bias
    k_mm2<<<GEMB, 256, 0, stream>>>(agA, agB, W2, b2, out);
}